// Round 17
// baseline (119.948 us; speedup 1.0000x reference)
//
#include <hip/hip_runtime.h>
#include <hip/hip_bf16.h>
#include <cstdint>
#include <cmath>

#define SEQ 2048
#define NH 16
#define DM 1024
#define BATCH 2

typedef short bf16x8 __attribute__((ext_vector_type(8)));
typedef float f32x4 __attribute__((ext_vector_type(4)));
typedef const void __attribute__((address_space(1)))* gas_t;
typedef void __attribute__((address_space(3)))* las_t;

#if __has_builtin(__builtin_amdgcn_exp2f)
#define EXP2(x) __builtin_amdgcn_exp2f(x)
#else
#define EXP2(x) __expf((x) * 0.6931471805599453f)
#endif

// Q prescale: (1/sqrt(64)) * log2(e) so scores are already in log2 domain
#define QSCALE 0.18033688011112042f

static __device__ __forceinline__ unsigned short f2bf(float f) {
    union { __hip_bfloat16 h; unsigned short u; } cv;
    cv.h = __float2bfloat16(f);
    return cv.u;
}
static __device__ __forceinline__ float bf2f(unsigned short u) {
    union { unsigned short u; __hip_bfloat16 h; } cv;
    cv.u = u;
    return __bfloat162float(cv.h);
}

static __device__ __forceinline__ void gload_lds16(const void* g, void* l) {
    __builtin_amdgcn_global_load_lds(
        reinterpret_cast<gas_t>(reinterpret_cast<uintptr_t>(g)),
        reinterpret_cast<las_t>(reinterpret_cast<uintptr_t>(l)),
        16, 0, 0);
}

// ---------------- fp32 -> bf16 convert + RoPE table, one launch ----------
__global__ __launch_bounds__(256) void cvt_all(
    const float* __restrict__ x,  const float* __restrict__ wq,
    const float* __restrict__ wk, const float* __restrict__ wv,
    const float* __restrict__ wo, const int* __restrict__ pos,
    unsigned short* __restrict__ xb, unsigned short* __restrict__ wqkv,
    unsigned short* __restrict__ wob, float2* __restrict__ tab) {
    int blk = blockIdx.x;
    if (blk >= 8192) {                       // RoPE cos/sin table
        int idx = (blk - 8192) * 256 + threadIdx.x;   // s*32 + i
        int s = idx >> 5, i = idx & 31;
        float fpos = (float)pos[s];
        float freq = exp2f(-(float)i * (13.287712379549449f / 32.0f));
        float ang = fpos * freq, sn, cs;
        sincosf(ang, &sn, &cs);
        tab[idx] = make_float2(cs, sn);
        return;
    }
    const float* src; unsigned short* dst; int base;
    if (blk < 4096)      { src = x;  dst = xb;              base = blk; }
    else if (blk < 5120) { src = wq; dst = wqkv;            base = blk - 4096; }
    else if (blk < 6144) { src = wk; dst = wqkv + 1048576;  base = blk - 5120; }
    else if (blk < 7168) { src = wv; dst = wqkv + 2097152;  base = blk - 6144; }
    else                 { src = wo; dst = wob;             base = blk - 7168; }
    int i = base * 256 + threadIdx.x;
    float4 v = reinterpret_cast<const float4*>(src)[i];
    ushort4 o;
    o.x = f2bf(v.x); o.y = f2bf(v.y); o.z = f2bf(v.z); o.w = f2bf(v.w);
    reinterpret_cast<ushort4*>(dst)[i] = o;
}

// ---------------- 128x128 bf16 GEMM: C = A * B^T ----------------
template<int OUT_BF16>
__global__ __launch_bounds__(256) void gemm_bt(
    const unsigned short* __restrict__ A,
    const unsigned short* __restrict__ B,
    void* __restrict__ C, int M, int N, int K) {
    __shared__ unsigned short As[128 * 32];
    __shared__ unsigned short Bs[128 * 32];
    const int tid = threadIdx.x;
    const int lane = tid & 63, wid = tid >> 6;
    const int wr = wid >> 1, wc = wid & 1;
    const int ln15 = lane & 15, kq = lane >> 4;
    const int bm = blockIdx.y, bn = blockIdx.x;

    f32x4 acc[4][4] = {};
    const int nk = K >> 5;
    for (int kt = 0; kt < nk; ++kt) {
        #pragma unroll
        for (int i = 0; i < 2; ++i) {
            int c = i * 256 + tid;
            int row = c >> 2, k8 = (c & 3) << 3;
            size_t gofsA = (size_t)(bm * 128 + row) * K + kt * 32 + k8;
            size_t gofsB = (size_t)(bn * 128 + row) * K + kt * 32 + k8;
            unsigned ldsoff_ = (unsigned)(i * 256 + wid * 64) * 16;  // wave-uniform
            gload_lds16(A + gofsA, (char*)As + ldsoff_);
            gload_lds16(B + gofsB, (char*)Bs + ldsoff_);
        }
        __syncthreads();
        bf16x8 af[4], bf[4];
        #pragma unroll
        for (int m = 0; m < 4; ++m)
            af[m] = *reinterpret_cast<const bf16x8*>(&As[(wr * 64 + m * 16 + ln15) * 32 + kq * 8]);
        #pragma unroll
        for (int n = 0; n < 4; ++n)
            bf[n] = *reinterpret_cast<const bf16x8*>(&Bs[(wc * 64 + n * 16 + ln15) * 32 + kq * 8]);
        #pragma unroll
        for (int m = 0; m < 4; ++m)
            #pragma unroll
            for (int n = 0; n < 4; ++n)
                acc[m][n] = __builtin_amdgcn_mfma_f32_16x16x32_bf16(af[m], bf[n], acc[m][n], 0, 0, 0);
        __syncthreads();
    }
    #pragma unroll
    for (int m = 0; m < 4; ++m) {
        #pragma unroll
        for (int n = 0; n < 4; ++n) {
            int col = bn * 128 + wc * 64 + n * 16 + ln15;
            #pragma unroll
            for (int j = 0; j < 4; ++j) {
                int row = bm * 128 + wr * 64 + m * 16 + kq * 4 + j;
                if constexpr (OUT_BF16 != 0)
                    ((unsigned short*)C)[(size_t)row * N + col] = f2bf(acc[m][n][j]);
                else
                    ((float*)C)[(size_t)row * N + col] = acc[m][n][j];
            }
        }
    }
}

// ---------------- RoPE + split qkv[B*S][3072] -> Qh,Kh [B,H,S,64] ----------------
__global__ __launch_bounds__(256) void rope_kernel(
    const unsigned short* __restrict__ qkv, const float2* __restrict__ tab,
    unsigned short* __restrict__ Qh, unsigned short* __restrict__ Kh) {
    int bs = blockIdx.x;            // b*SEQ + s
    int b = bs >> 11, s = bs & (SEQ - 1);
    int t = threadIdx.x;
    #pragma unroll
    for (int p = t; p < 512; p += 256) {
        int h = p >> 5, i = p & 31;
        float2 cs = tab[(s << 5) + i];
        size_t src = (size_t)bs * 3072 + h * 64 + 2 * i;
        size_t dst = ((size_t)(b * NH + h) * SEQ + s) * 64 + 2 * i;
        ushort2 qv = *reinterpret_cast<const ushort2*>(qkv + src);
        float q0 = bf2f(qv.x), q1 = bf2f(qv.y);
        ushort2 qo;
        qo.x = f2bf((q0 * cs.x - q1 * cs.y) * QSCALE);
        qo.y = f2bf((q1 * cs.x + q0 * cs.y) * QSCALE);
        *reinterpret_cast<ushort2*>(Qh + dst) = qo;
        ushort2 kv = *reinterpret_cast<const ushort2*>(qkv + src + 1024);
        float k0 = bf2f(kv.x), k1 = bf2f(kv.y);
        ushort2 ko;
        ko.x = f2bf(k0 * cs.x - k1 * cs.y);
        ko.y = f2bf(k1 * cs.x + k0 * cs.y);
        *reinterpret_cast<ushort2*>(Kh + dst) = ko;
    }
}

// ---------------- V: qkv cols 2048.. -> [B,H,64,S] (tiled transpose) ----------------
__global__ __launch_bounds__(256) void vtrans_kernel(
    const unsigned short* __restrict__ qkv, unsigned short* __restrict__ Vo) {
    __shared__ unsigned short tile[64][65];
    int blk = blockIdx.x;           // (b*NH + h)*32 + st
    int st = blk & 31, bh = blk >> 5;
    int sb = st * 64;
    int t = threadIdx.x;
    int b = bh >> 4, h = bh & 15;
    #pragma unroll
    for (int u = t; u < 1024; u += 256) {
        int sl = u >> 4, d4 = (u & 15) << 2;
        ushort4 v = *reinterpret_cast<const ushort4*>(
            qkv + (size_t)(b * SEQ + sb + sl) * 3072 + 2048 + h * 64 + d4);
        tile[sl][d4] = v.x; tile[sl][d4 + 1] = v.y;
        tile[sl][d4 + 2] = v.z; tile[sl][d4 + 3] = v.w;
    }
    __syncthreads();
    #pragma unroll
    for (int u = t; u < 1024; u += 256) {
        int d = u >> 4, s4 = (u & 15) << 2;
        ushort4 o;
        o.x = tile[s4][d]; o.y = tile[s4 + 1][d];
        o.z = tile[s4 + 2][d]; o.w = tile[s4 + 3][d];
        *reinterpret_cast<ushort4*>(Vo + ((size_t)bh * 64 + d) * SEQ + sb + s4) = o;
    }
}

// ---------------- causal flash attention, KVBLK=64, 4 waves, uniform pairs ----
// r16's measured-best version, byte-identical.
__global__ __launch_bounds__(256) void attn_kernel(
    const unsigned short* __restrict__ Qh, const unsigned short* __restrict__ Kh,
    const unsigned short* __restrict__ Vt, unsigned short* __restrict__ Out) {
    __shared__ unsigned short Kb[2][64 * 64];   // [k][d], chunk-swizzled rows
    __shared__ unsigned short Vb[2][64 * 64];   // [d][k], chunk-swizzled rows
    __shared__ unsigned short Plds[4][16 * 72]; // per-wave P

    const int tid = threadIdx.x;
    const int wid = tid >> 6, lane = tid & 63;
    const int ln15 = lane & 15, g = lane >> 4;
    const int bid = blockIdx.x;
    const int bh = bid & 31;
    const int pb = bid >> 5;                    // 0..15 -> bands {pb, 31-pb}

    const unsigned short* Qp = Qh + (size_t)bh * SEQ * 64;
    const unsigned short* Kp = Kh + (size_t)bh * SEQ * 64;
    const unsigned short* Vp = Vt + (size_t)bh * 64 * SEQ;
    char* Pc = (char*)Plds[wid];

    // staging: 512 chunks x 16B per 64x64 tile; 256 threads x 2 chunks each
    const unsigned short* kSrc[2];
    const unsigned short* vSrc[2];
    #pragma unroll
    for (int p = 0; p < 2; ++p) {
        int c = tid + (p << 8);
        int row = c >> 3, slot = c & 7;
        kSrc[p] = Kp + (size_t)row * 64 + ((slot ^ (row & 7)) << 3);
        vSrc[p] = Vp + (size_t)row * SEQ + ((slot ^ (row & 7)) << 3);
    }
    auto stage = [&](int kb, int buf) {   // 4 gload_lds per thread
        #pragma unroll
        for (int p = 0; p < 2; ++p) {
            unsigned bb = (unsigned)((tid + (p << 8)) << 4);
            gload_lds16(kSrc[p] + (size_t)kb * 64, (char*)Kb[buf] + bb);
            gload_lds16(vSrc[p] + kb, (char*)Vb[buf] + bb);
        }
    };

    unsigned kOff[4][2], vOff[4][2];
    #pragma unroll
    for (int s = 0; s < 4; ++s) {
        int r = ln15 + 16 * s;
        kOff[s][0] = r * 128 + ((g ^ (r & 7)) << 4);
        kOff[s][1] = r * 128 + (((4 + g) ^ (r & 7)) << 4);
    }
    #pragma unroll
    for (int c = 0; c < 4; ++c) {
        int d = c * 16 + ln15;
        vOff[c][0] = d * 128 + ((g ^ (d & 7)) << 4);
        vOff[c][1] = d * 128 + (((4 + g) ^ (d & 7)) << 4);
    }
    const unsigned pW = (unsigned)(ln15 * 144 + 8 * g);   // + 32*s for quarter s
    const unsigned pR = (unsigned)(ln15 * 144 + 16 * g);  // + 64*h for half h

    const int b = bh >> 4, h = bh & 15;

    for (int bi = 0; bi < 2; ++bi) {
        const int bnd = bi ? (31 - pb) : pb;
        const int qb = bnd * 64 + wid * 16;
        const int nt = bnd + 1;                 // 64-wide k-tiles
        const int thr = qb + ln15 - 4 * g;      // allowed: kb + 16s + 4g + j <= qb + ln15

        bf16x8 aq0 = *reinterpret_cast<const bf16x8*>(Qp + (size_t)(qb + ln15) * 64 + g * 8);
        bf16x8 aq1 = *reinterpret_cast<const bf16x8*>(Qp + (size_t)(qb + ln15) * 64 + 32 + g * 8);

        f32x4 oacc[4] = {};
        float lsum = 0.f;

        stage(0, 0);   // band prologue

        for (int t = 0; t < nt; ++t) {
            const int kb = t << 6;
            const int cur = t & 1;
            if (t + 1 < nt) {
                stage((t + 1) << 6, cur ^ 1);
                asm volatile("s_waitcnt vmcnt(4)" ::: "memory");  // tile t's 4 done
            } else {
                asm volatile("s_waitcnt vmcnt(0)" ::: "memory");
            }
            __builtin_amdgcn_s_barrier();

            const char* K0 = (const char*)Kb[cur];
            const char* V0 = (const char*)Vb[cur];
            bf16x8 kf[8], bv[8];
            #pragma unroll
            for (int s = 0; s < 4; ++s) {
                kf[2 * s]     = *reinterpret_cast<const bf16x8*>(K0 + kOff[s][0]);
                kf[2 * s + 1] = *reinterpret_cast<const bf16x8*>(K0 + kOff[s][1]);
            }
            #pragma unroll
            for (int c = 0; c < 4; ++c) {
                bv[2 * c]     = *reinterpret_cast<const bf16x8*>(V0 + vOff[c][0]);
                bv[2 * c + 1] = *reinterpret_cast<const bf16x8*>(V0 + vOff[c][1]);
            }

            const f32x4 z = {};
            f32x4 sq[4];
            #pragma unroll
            for (int s = 0; s < 4; ++s) {
                sq[s] = __builtin_amdgcn_mfma_f32_16x16x32_bf16(kf[2 * s], aq0, z, 0, 0, 0);
                sq[s] = __builtin_amdgcn_mfma_f32_16x16x32_bf16(kf[2 * s + 1], aq1, sq[s], 0, 0, 0);
            }

            float pv[4][4];
            if (t == nt - 1) {      // boundary tile: causal mask
                #pragma unroll
                for (int s = 0; s < 4; ++s)
                    #pragma unroll
                    for (int j = 0; j < 4; ++j)
                        pv[s][j] = (j <= thr - kb - 16 * s) ? EXP2(sq[s][j]) : 0.f;
            } else {
                #pragma unroll
                for (int s = 0; s < 4; ++s)
                    #pragma unroll
                    for (int j = 0; j < 4; ++j)
                        pv[s][j] = EXP2(sq[s][j]);
            }
            #pragma unroll
            for (int s = 0; s < 4; ++s)
                lsum += (pv[s][0] + pv[s][1]) + (pv[s][2] + pv[s][3]);

            #pragma unroll
            for (int s = 0; s < 4; ++s) {
                ushort4 w;
                w.x = f2bf(pv[s][0]); w.y = f2bf(pv[s][1]);
                w.z = f2bf(pv[s][2]); w.w = f2bf(pv[s][3]);
                *reinterpret_cast<ushort4*>(Pc + pW + 32 * s) = w;
            }
            asm volatile("s_waitcnt lgkmcnt(0)" ::: "memory");
            bf16x8 ap0 = *reinterpret_cast<const bf16x8*>(Pc + pR);
            bf16x8 ap1 = *reinterpret_cast<const bf16x8*>(Pc + pR + 64);
            #pragma unroll
            for (int c = 0; c < 4; ++c) {
                oacc[c] = __builtin_amdgcn_mfma_f32_16x16x32_bf16(ap0, bv[2 * c], oacc[c], 0, 0, 0);
                oacc[c] = __builtin_amdgcn_mfma_f32_16x16x32_bf16(ap1, bv[2 * c + 1], oacc[c], 0, 0, 0);
            }
            asm volatile("s_waitcnt lgkmcnt(0)" ::: "memory");  // buf[cur] reads done
            __builtin_amdgcn_s_barrier();
        }

        // normalize + store this band
        float r = lsum;
        r += __shfl_xor(r, 16);
        r += __shfl_xor(r, 32);
        float linv = 1.f / r;
        float invj[4];
        #pragma unroll
        for (int j = 0; j < 4; ++j)
            invj[j] = __shfl(linv, 20 * g + j);   // lane with ln15 == 4g+j
        #pragma unroll
        for (int c = 0; c < 4; ++c)
            #pragma unroll
            for (int j = 0; j < 4; ++j) {
                int s = qb + g * 4 + j;
                Out[((size_t)(b * SEQ + s)) * DM + h * 64 + c * 16 + ln15] =
                    f2bf(oacc[c][j] * invj[j]);
            }
    }
}

extern "C" void kernel_launch(void* const* d_in, const int* in_sizes, int n_in,
                              void* d_out, int out_size, void* d_ws, size_t ws_size,
                              hipStream_t stream) {
    const float* x = (const float*)d_in[0];
    const int* pos = (const int*)d_in[1];
    const float* Wq = (const float*)d_in[2];
    const float* Wk = (const float*)d_in[3];
    const float* Wv = (const float*)d_in[4];
    const float* Wo = (const float*)d_in[5];
    float* out = (float*)d_out;

    char* ws = (char*)d_ws;
    const size_t MB = 1024 * 1024;
    unsigned short* xb   = (unsigned short*)(ws + 0 * MB);
    unsigned short* wqkv = (unsigned short*)(ws + 8 * MB);   // wq|wk|wv contiguous
    unsigned short* wob  = (unsigned short*)(ws + 14 * MB);
    unsigned short* qkv  = (unsigned short*)(ws + 16 * MB);  // [4096][3072]
    float2*         tab  = (float2*)       (ws + 40 * MB);   // [2048][32]
    unsigned short* qh   = (unsigned short*)(ws + 41 * MB);
    unsigned short* kh   = (unsigned short*)(ws + 49 * MB);
    unsigned short* vtr  = (unsigned short*)(ws + 57 * MB);
    unsigned short* att  = (unsigned short*)(ws + 65 * MB);

    cvt_all<<<8448, 256, 0, stream>>>(x, Wq, Wk, Wv, Wo, pos, xb, wqkv, wob, tab);

    gemm_bt<1><<<dim3(24, 32), 256, 0, stream>>>(xb, wqkv, qkv, 4096, 3072, 1024);

    rope_kernel<<<4096, 256, 0, stream>>>(qkv, tab, qh, kh);
    vtrans_kernel<<<1024, 256, 0, stream>>>(qkv, vtr);

    attn_kernel<<<512, 256, 0, stream>>>(qh, kh, vtr, att);

    gemm_bt<0><<<dim3(8, 32), 256, 0, stream>>>(att, wob, out, 4096, 1024, 1024);
}